// Round 7
// baseline (433.997 us; speedup 1.0000x reference)
//
#include <hip/hip_runtime.h>
#include <hip/hip_bf16.h>
#include <hip/hip_fp16.h>

#define Hh 56
#define Ww 56
#define Cc 256
#define Tt 16
#define Bb 4
#define Nn 3136
#define Kk 784
#define KX 28
#define Dd 128
#define Mc 64
#define NTOP 32

typedef __attribute__((ext_vector_type(8))) _Float16 f16x8;
typedef __attribute__((ext_vector_type(4))) float f32x4;

// ---- K_prep: fused {wc (blocks 0..255), coords (256..271), dcinit (272..320)}
__global__ __launch_bounds__(256) void k_prep(
    const float* __restrict__ pw_w, const float* __restrict__ pw_b,
    const float* __restrict__ proj_w, const float* __restrict__ proj_b,
    const float* __restrict__ Abank,
    float* __restrict__ wct, float* __restrict__ bc,
    unsigned* __restrict__ offo, float2* __restrict__ wo,
    float* __restrict__ dc) {
  int blk = blockIdx.x;
  if (blk < 256) {
    // ---- wc: combined weight Wc^T [c][d] and bias bc ----
    int c = blk;
    int d = threadIdx.x;
    if (d < 128) {
      float acc = 0.f;
      for (int m = 0; m < Mc; ++m) acc += proj_w[d * Mc + m] * pw_w[m * Cc + c];
      wct[c * Dd + d] = acc;
      if (c == 0) {
        float bb = proj_b[d];
        for (int m = 0; m < Mc; ++m) bb += proj_w[d * Mc + m] * pw_b[m];
        bc[d] = bb;
      }
    }
  } else if (blk < 272) {
    // ---- coords: per-t warp taps, computed once ----
    int t = blk - 256;
    const float* A = Abank + t * 6;
    float a00 = A[0], a01 = A[1], a02 = A[2], a10 = A[3], a11 = A[4], a12 = A[5];
    for (int e = threadIdx.x; e < Nn; e += 256) {
      int h = e / 56, w = e - h * 56;
      float gx = (2.0f * w + 1.0f) / 56.0f - 1.0f;
      float gy = (2.0f * h + 1.0f) / 56.0f - 1.0f;
      float u = a00 * gx + a01 * gy + a02;
      float v = a10 * gx + a11 * gy + a12;
      float ix = ((u + 1.0f) * 56.0f - 1.0f) * 0.5f;
      float iy = ((v + 1.0f) * 56.0f - 1.0f) * 0.5f;
      float x0f = floorf(ix), y0f = floorf(iy);
      int x0 = (int)x0f, y0 = (int)y0f;
      int x0c = min(max(x0, 0), 55), x1c = min(max(x0 + 1, 0), 55);
      int y0c = min(max(y0, 0), 55), y1c = min(max(y0 + 1, 0), 55);
      offo[t * Nn + e] = (y0c * 56 + x0c) | ((x1c - x0c) << 12) | ((y1c - y0c) << 13);
      float2 wv2;
      wv2.x = ix - x0f;
      wv2.y = iy - y0f;
      wo[t * Nn + e] = wv2;
    }
  } else {
    // ---- dcinit ----
    int i = (blk - 272) * 256 + threadIdx.x;
    if (i < Bb * Nn) dc[i] = (float)Nn;
  }
}

// ---- K_mix: channel mix FIRST, pair-interleaved output. b128 LDS reads ------
// grid: b(4) x ntile(98 of 32) = 392 blocks, 256 thr
__global__ __launch_bounds__(256) void k_mix(
    const float* __restrict__ fm, const float* __restrict__ wct, float* __restrict__ y) {
  int blk = blockIdx.x;
  int b = blk / 98;
  int n0 = (blk % 98) * 32;
  int tid = threadIdx.x;
  int d = tid & 127;
  int ng = tid >> 7;               // 0..1 -> k-half of 16
  __shared__ __align__(16) float fm_s[64][32];
  __shared__ float wc_s[64 * Dd];
  float acc[16];
#pragma unroll
  for (int j = 0; j < 16; ++j) acc[j] = 0.f;
  const float* fb = fm + (size_t)b * Cc * Nn;
  for (int c0 = 0; c0 < Cc; c0 += 64) {
    for (int i = tid; i < 64 * 32; i += 256) {
      int c = i >> 5, kx = i & 31;
      fm_s[c][kx] = fb[(size_t)(c0 + c) * Nn + n0 + kx];
    }
    for (int i = tid; i < 64 * Dd; i += 256) wc_s[i] = wct[c0 * Dd + i];
    __syncthreads();
    for (int c = 0; c < 64; ++c) {
      float w = wc_s[c * Dd + d];
      const float4* fr = reinterpret_cast<const float4*>(&fm_s[c][ng * 16]);
      float4 f0 = fr[0], f1 = fr[1], f2 = fr[2], f3 = fr[3];
      acc[0]  += f0.x * w; acc[1]  += f0.y * w; acc[2]  += f0.z * w; acc[3]  += f0.w * w;
      acc[4]  += f1.x * w; acc[5]  += f1.y * w; acc[6]  += f1.z * w; acc[7]  += f1.w * w;
      acc[8]  += f2.x * w; acc[9]  += f2.y * w; acc[10] += f2.z * w; acc[11] += f2.w * w;
      acc[12] += f3.x * w; acc[13] += f3.y * w; acc[14] += f3.z * w; acc[15] += f3.w * w;
    }
    __syncthreads();
  }
  size_t base = (((size_t)b * 64 + (d >> 1)) * Nn + n0 + ng * 16) * 2 + (d & 1);
#pragma unroll
  for (int j = 0; j < 16; ++j) y[base + 2 * j] = acc[j];
}

// ---- K1: fused warp+bilinear+9x9/s2 pool, 4 channel-pairs per block ---------
// grid: b(4) x pg(16, 4 pairs each) x t(16) = 1024 blocks, 256 thr
// (4 blocks/CU exactly at 37.6KB LDS; tap tables loaded once per 8 channels)
__global__ __launch_bounds__(256) void k_fused_pool(
    const float* __restrict__ yraw, const unsigned* __restrict__ offo,
    const float2* __restrict__ wo, const float* __restrict__ bc,
    float* __restrict__ zt) {
  const float2* y2 = reinterpret_cast<const float2*>(yraw);
  int idx = blockIdx.x;
  int b = idx & 3;
  int pg = (idx >> 2) & 15;
  int t = idx >> 6;
  __shared__ float2 wsm[3136];
  __shared__ float2 rowp[1568];
  int tid = threadIdx.x;
  const unsigned* offp = offo + t * Nn;
  const float2* wp = wo + t * Nn;
  unsigned off[13];
  float2 wv[13];
#pragma unroll
  for (int j = 0; j < 13; ++j) {
    int e = tid + 256 * j;
    if (e < 3136) {
      off[j] = offp[e];
      wv[j] = wp[e];
    }
  }
  for (int pp = 0; pp < 4; ++pp) {
    int dp = pg * 4 + pp;                       // channel pair 0..63
    const float2* fc = y2 + ((size_t)b * 64 + dp) * Nn;
    float b0 = bc[dp * 2], b1 = bc[dp * 2 + 1];
#pragma unroll
    for (int j = 0; j < 13; ++j) {
      int e = tid + 256 * j;
      if (e < 3136) {
        unsigned pk = off[j];
        int base = pk & 4095;
        int dx = (pk >> 12) & 1;
        int dyy = (pk & (1u << 13)) ? 56 : 0;
        float2 v00 = fc[base], v01 = fc[base + dx];
        float2 v10 = fc[base + dyy], v11 = fc[base + dyy + dx];
        float wx = wv[j].x, wy = wv[j].y;
        float tx = v00.x + wx * (v01.x - v00.x);
        float bx = v10.x + wx * (v11.x - v10.x);
        float ty = v00.y + wx * (v01.y - v00.y);
        float by = v10.y + wx * (v11.y - v10.y);
        float2 o;
        o.x = tx + wy * (bx - tx);
        o.y = ty + wy * (by - ty);
        wsm[e] = o;
      }
    }
    __syncthreads();
    for (int e = tid; e < 1568; e += 256) {
      int h = e / 28, kx = e - h * 28;
      int xs = 2 * kx - 4;
      int lo = max(xs, 0), hi = min(xs + 8, 55);
      float sx = 0.f, sy = 0.f;
      const float2* wr = wsm + h * 56;
      for (int x = lo; x <= hi; ++x) { float2 v = wr[x]; sx += v.x; sy += v.y; }
      float2 o; o.x = sx; o.y = sy;
      rowp[e] = o;
    }
    __syncthreads();
    float* zo0 = zt + ((size_t)(t * Bb + b) * Dd + dp * 2) * Kk;
    float* zo1 = zo0 + Kk;
    for (int e = tid; e < 784; e += 256) {
      int ky = e / 28, kx = e - ky * 28;
      int ys = 2 * ky - 4;
      int lo = max(ys, 0), hi = min(ys + 8, 55);
      float sx = 0.f, sy = 0.f;
      for (int h = lo; h <= hi; ++h) { float2 rv = rowp[h * 28 + kx]; sx += rv.x; sy += rv.y; }
      zo0[e] = sx * (1.0f / 81.0f) + b0;
      zo1[e] = sy * (1.0f / 81.0f) + b1;
    }
    __syncthreads();
  }
}

// ---- K4: transpose zt -> z (normalized, [tb][k][d]) + s = zn . r ------------
__global__ __launch_bounds__(256) void k_znorm(
    const float* __restrict__ zt, const float* __restrict__ r,
    float* __restrict__ z, float* __restrict__ s_arr) {
  int tb = blockIdx.x / 14;
  int k0 = (blockIdx.x % 14) * 56;
  int tid = threadIdx.x;
  __shared__ float ls[56 * 129];
  const float* zb = zt + (size_t)tb * Dd * Kk + k0;
  for (int i = tid; i < Dd * 56; i += 256) {
    int d = i / 56, kk = i - d * 56;
    ls[kk * 129 + d] = zb[(size_t)d * Kk + kk];
  }
  int lane = tid & 63;
  int wvv = tid >> 6;              // 0..3
  float r0 = r[lane], r1 = r[lane + 64];
  __syncthreads();
  for (int p = 0; p < 14; ++p) {
    int k = p * 4 + wvv;
    float z0 = ls[k * 129 + lane];
    float z1 = ls[k * 129 + 64 + lane];
    float ss = z0 * z0 + z1 * z1;
    for (int off = 32; off; off >>= 1) ss += __shfl_xor(ss, off);
    float inv = 1.0f / fmaxf(sqrtf(ss), 1e-6f);
    z0 *= inv; z1 *= inv;
    float* zr = z + ((size_t)tb * Kk + k0 + k) * Dd;
    zr[lane] = z0;
    zr[lane + 64] = z1;
    float sd = z0 * r0 + z1 * r1;
    for (int off = 32; off; off >>= 1) sd += __shfl_xor(sd, off);
    if (lane == 0) s_arr[(size_t)tb * Kk + k0 + k] = sd;
  }
}

// ---------------- K5: softmax over T, g_emb ----------------------------------
__global__ __launch_bounds__(128) void k_gemb(
    const float* __restrict__ z, const float* __restrict__ s_arr, float* __restrict__ g) {
  int blk = blockIdx.x;            // b*784 + k
  int b = blk / Kk, k = blk % Kk;
  int d = threadIdx.x;
  float sv[Tt];
  float mx = -3.4e38f;
#pragma unroll
  for (int t = 0; t < Tt; ++t) {
    sv[t] = s_arr[(t * Bb + b) * Kk + k];
    mx = fmaxf(mx, sv[t]);
  }
  float sum = 0.f;
#pragma unroll
  for (int t = 0; t < Tt; ++t) {
    sv[t] = expf(10.0f * (sv[t] - mx));
    sum += sv[t];
  }
  float isum = 1.0f / sum;
  float acc = 0.f;
#pragma unroll
  for (int t = 0; t < Tt; ++t)
    acc += sv[t] * isum * z[((size_t)(t * Bb + b) * Kk + k) * Dd + d];
  g[((size_t)b * Kk + k) * Dd + d] = acc;
}

// ---- K6: E = normalize(M @ g), also emits fp16 copy. 2 rows per block -------
__global__ __launch_bounds__(128) void k_E(
    const float* __restrict__ Mmat, const float* __restrict__ g,
    float* __restrict__ E, _Float16* __restrict__ E16) {
  int row = blockIdx.x * 2 + (threadIdx.x >> 6);   // b*N + n
  int b = row / Nn, n = row % Nn;
  int y = n / Ww, x = n % Ww;
  int x0 = x >> 1, y0 = y >> 1;
  int x1 = min(x0 + 1, 27), y1 = min(y0 + 1, 27);
  bool hx = (x1 != x0), hy = (y1 != y0);
  int k00 = y0 * 28 + x0, k01 = y0 * 28 + x1, k10 = y1 * 28 + x0, k11 = y1 * 28 + x1;
  const float* Mr = Mmat + (size_t)n * Kk;
  float m00 = Mr[k00];
  float m01 = hx ? Mr[k01] : 0.f;
  float m10 = hy ? Mr[k10] : 0.f;
  float m11 = (hx && hy) ? Mr[k11] : 0.f;
  const float* gb = g + (size_t)b * Kk * Dd;
  int lane = threadIdx.x & 63;
  int l2 = lane + 64;
  float a0 = m00 * gb[k00 * Dd + lane] + m01 * gb[k01 * Dd + lane] +
             m10 * gb[k10 * Dd + lane] + m11 * gb[k11 * Dd + lane];
  float a1 = m00 * gb[k00 * Dd + l2] + m01 * gb[k01 * Dd + l2] +
             m10 * gb[k10 * Dd + l2] + m11 * gb[k11 * Dd + l2];
  float ss = a0 * a0 + a1 * a1;
  for (int off = 32; off; off >>= 1) ss += __shfl_xor(ss, off);
  float inv = 1.0f / fmaxf(sqrtf(ss), 1e-6f);
  float e0 = a0 * inv, e1 = a1 * inv;
  E[(size_t)row * Dd + lane] = e0;
  E[(size_t)row * Dd + l2] = e1;
  E16[(size_t)row * Dd + lane] = (_Float16)e0;
  E16[(size_t)row * Dd + l2] = (_Float16)e1;
}

// ---- K7: Saff = (E E^T) * G -> fp16 via MFMA f16 (fp32 accum) ---------------
// Both main and mirror stores go through LDS tiles -> coalesced 128B uint rows.
__global__ __launch_bounds__(256) void k_saff(
    const _Float16* __restrict__ E16, __half* __restrict__ S) {
  int blk = blockIdx.x;
  int b = blk / 1225;
  int rem = blk % 1225;
  int ti0 = (int)((sqrtf(8.f * rem + 1.f) - 1.f) * 0.5f);
  while ((ti0 + 1) * (ti0 + 2) / 2 <= rem) ++ti0;
  while (ti0 * (ti0 + 1) / 2 > rem) --ti0;
  int tj0 = rem - ti0 * (ti0 + 1) / 2;   // tj0 <= ti0
  int i0 = ti0 * 64, j0 = tj0 * 64;
  int wave = threadIdx.x >> 6, lane = threadIdx.x & 63;
  int wr = wave >> 1, wc = wave & 1;
  int lr = lane & 15, lk = lane >> 4;    // frag row/col, k-group
  int ibase = i0 + wr * 32;
  int jbase = j0 + wc * 32;
  const _Float16* Eb = E16 + (size_t)b * Nn * Dd;
  __shared__ __half tileT[64][66];       // [j][i] for mirror store
  __shared__ __half tileR[64][66];       // [i][j] for main store
  f32x4 acc00 = {0.f, 0.f, 0.f, 0.f};
  f32x4 acc01 = acc00, acc10 = acc00, acc11 = acc00;
#pragma unroll
  for (int ks = 0; ks < 4; ++ks) {
    int ko = ks * 32 + lk * 8;
    f16x8 a0 = *reinterpret_cast<const f16x8*>(Eb + (size_t)(ibase + lr) * Dd + ko);
    f16x8 a1 = *reinterpret_cast<const f16x8*>(Eb + (size_t)(ibase + 16 + lr) * Dd + ko);
    f16x8 b0 = *reinterpret_cast<const f16x8*>(Eb + (size_t)(jbase + lr) * Dd + ko);
    f16x8 b1 = *reinterpret_cast<const f16x8*>(Eb + (size_t)(jbase + 16 + lr) * Dd + ko);
    acc00 = __builtin_amdgcn_mfma_f32_16x16x32_f16(a0, b0, acc00, 0, 0, 0);
    acc01 = __builtin_amdgcn_mfma_f32_16x16x32_f16(a0, b1, acc01, 0, 0, 0);
    acc10 = __builtin_amdgcn_mfma_f32_16x16x32_f16(a1, b0, acc10, 0, 0, 0);
    acc11 = __builtin_amdgcn_mfma_f32_16x16x32_f16(a1, b1, acc11, 0, 0, 0);
  }
  size_t ob = (size_t)b * Nn * Nn;
  int gj[2];
  float xj[2], yj[2];
#pragma unroll
  for (int tj = 0; tj < 2; ++tj) {
    gj[tj] = jbase + tj * 16 + lr;
    int yv = gj[tj] / 56;
    yj[tj] = (float)yv;
    xj[tj] = (float)(gj[tj] - yv * 56);
  }
  bool mirror = (i0 != j0);
#pragma unroll
  for (int ti = 0; ti < 2; ++ti) {
#pragma unroll
    for (int q = 0; q < 4; ++q) {
      int iloc = wr * 32 + ti * 16 + lk * 4 + q;
      int gi = i0 + iloc;
      int yiv = gi / 56;
      float yi = (float)yiv;
      float xi = (float)(gi - yiv * 56);
#pragma unroll
      for (int tj = 0; tj < 2; ++tj) {
        float a;
        if (ti == 0 && tj == 0) a = acc00[q];
        else if (ti == 0 && tj == 1) a = acc01[q];
        else if (ti == 1 && tj == 0) a = acc10[q];
        else a = acc11[q];
        float dx = xi - xj[tj];
        float dy = yi - yj[tj];
        float gg = 1.0f - __expf(-(dx * dx + dy * dy) * (1.0f / 18.0f));
        __half hv = __float2half(a * gg);
        int jloc = wc * 32 + tj * 16 + lr;
        tileR[iloc][jloc] = hv;
        tileT[jloc][iloc] = hv;
      }
    }
  }
  __syncthreads();
  for (int e = threadIdx.x; e < 64 * 32; e += 256) {
    int row = e >> 5, c2 = e & 31;
    unsigned v = *reinterpret_cast<const unsigned*>(&tileR[row][c2 * 2]);
    *reinterpret_cast<unsigned*>(&S[ob + (size_t)(i0 + row) * Nn + j0 + c2 * 2]) = v;
  }
  if (mirror) {
    for (int e = threadIdx.x; e < 64 * 32; e += 256) {
      int row = e >> 5, c2 = e & 31;
      unsigned v = *reinterpret_cast<const unsigned*>(&tileT[row][c2 * 2]);
      *reinterpret_cast<unsigned*>(&S[ob + (size_t)(j0 + row) * Nn + i0 + c2 * 2]) = v;
    }
  }
}

// ---- K8: exact top-32 per row: 2-pass radix select on fp16 keys (wave-scan),
//      then exact fp32 recompute of the 32 selected values from E ------------
__global__ __launch_bounds__(256) void k_topk(
    const __half* __restrict__ S16, const float* __restrict__ E,
    const float* __restrict__ P, float* __restrict__ topv, int* __restrict__ topi,
    float* __restrict__ dr, float* __restrict__ dc) {
  int row = blockIdx.x;
  int b = row / Nn, irow = row % Nn;
  int tid = threadIdx.x;
  const unsigned* Sr = reinterpret_cast<const unsigned*>(S16 + (size_t)row * Nn);
  __shared__ unsigned hist[256 * 8];
  __shared__ unsigned wtot[4];
  __shared__ unsigned bcast[2];
  __shared__ unsigned sel_eq, sel_slot;
  __shared__ int sel_idx[NTOP];
  __shared__ float drow_s;
  unsigned pk[7];                  // 2 fp16 monotone keys per u32
#pragma unroll
  for (int j = 0; j < 7; ++j) {
    int c2 = tid + 256 * j;
    unsigned u = (c2 < Nn / 2) ? Sr[c2] : 0u;
    unsigned h0 = u & 0xFFFFu, h1 = u >> 16;
    unsigned k0 = h0 ^ ((h0 & 0x8000u) ? 0xFFFFu : 0x8000u);
    unsigned k1 = h1 ^ ((h1 & 0x8000u) ? 0xFFFFu : 0x8000u);
    if (c2 >= Nn / 2) { k0 = 0u; k1 = 0u; }
    pk[j] = k0 | (k1 << 16);
  }
  if (tid == 0) { sel_eq = 0; sel_slot = 0; drow_s = 0.f; }
  int lane = tid & 63, wvq = tid >> 6;
  unsigned prefix = 0;
  unsigned k = NTOP;
  for (int pass = 0; pass < 2; ++pass) {
    int shift = 8 - 8 * pass;
    unsigned pmask = pass ? 0xFF00u : 0u;
#pragma unroll
    for (int i = 0; i < 8; ++i) hist[tid * 8 + i] = 0;
    __syncthreads();
#pragma unroll
    for (int j = 0; j < 7; ++j) {
      unsigned k0 = pk[j] & 0xFFFFu, k1 = pk[j] >> 16;
      if ((k0 & pmask) == (prefix & pmask))
        atomicAdd(&hist[((k0 >> shift) & 255u) * 8 + (tid & 7)], 1u);
      if ((k1 & pmask) == (prefix & pmask))
        atomicAdd(&hist[((k1 >> shift) & 255u) * 8 + (tid & 7)], 1u);
    }
    __syncthreads();
    unsigned cnt = 0;
#pragma unroll
    for (int i = 0; i < 8; ++i) cnt += hist[tid * 8 + i];
    unsigned run = cnt;
#pragma unroll
    for (int off2 = 1; off2 < 64; off2 <<= 1) {
      unsigned v = __shfl_down(run, off2);
      if (lane + off2 < 64) run += v;
    }
    if (lane == 0) wtot[wvq] = run;  // wave total
    __syncthreads();
    unsigned hi = 0;
    for (int w2 = wvq + 1; w2 < 4; ++w2) hi += wtot[w2];
    unsigned incl = run + hi;
    unsigned excl = incl - cnt;
    if (excl < k && k <= incl) {
      bcast[0] = prefix | ((unsigned)tid << shift);
      bcast[1] = k - excl;
    }
    __syncthreads();
    prefix = bcast[0];
    k = bcast[1];
    __syncthreads();
  }
  unsigned T = prefix;
#pragma unroll
  for (int j = 0; j < 7; ++j) {
    int c2 = tid + 256 * j;
    if (c2 < Nn / 2) {
      unsigned k0 = pk[j] & 0xFFFFu, k1 = pk[j] >> 16;
      bool take0 = (k0 > T) || (k0 == T && atomicAdd(&sel_eq, 1u) < k);
      if (take0) { unsigned slot = atomicAdd(&sel_slot, 1u); sel_idx[slot] = 2 * c2; }
      bool take1 = (k1 > T) || (k1 == T && atomicAdd(&sel_eq, 1u) < k);
      if (take1) { unsigned slot = atomicAdd(&sel_slot, 1u); sel_idx[slot] = 2 * c2 + 1; }
    }
  }
  __syncthreads();
  // exact recompute: 8 threads per selected entry
  int sel = tid >> 3, part = tid & 7;
  int col = sel_idx[sel];
  const float* Ei = E + ((size_t)b * Nn + irow) * Dd;
  const float* Ej = E + ((size_t)b * Nn + col) * Dd;
  float v = 0.f;
#pragma unroll
  for (int d0 = 0; d0 < 16; ++d0) {
    int d = part * 16 + d0;
    v += Ei[d] * Ej[d];
  }
  v += __shfl_xor(v, 1);
  v += __shfl_xor(v, 2);
  v += __shfl_xor(v, 4);
  if (part == 0) {
    float dx = P[irow * 2] - P[col * 2];
    float dy = P[irow * 2 + 1] - P[col * 2 + 1];
    float gg = 1.0f - __expf(-(dx * dx + dy * dy) * (1.0f / 18.0f));
    v *= gg;
    topv[(size_t)row * NTOP + sel] = v;
    topi[(size_t)row * NTOP + sel] = col;
    float e = __expf(10.f * v);
    atomicAdd(&dc[b * Nn + col], e - 1.f);
    atomicAdd(&drow_s, e);
  }
  __syncthreads();
  if (tid == 0) dr[row] = (float)(Nn - NTOP) + drow_s;
}

__global__ void k_inv(float* __restrict__ dr, float* __restrict__ dc) {
  int i = blockIdx.x * 256 + threadIdx.x;
  if (i < Bb * Nn) {
    dr[i] = 1.0f / dr[i];
    dc[i] = 1.0f / dc[i];
  }
}

// ---------------- K10: A0 row = invdr_i * invdc_j, then fix 32 entries -------
__global__ __launch_bounds__(256) void k_basefix(
    const float* __restrict__ invdr, const float* __restrict__ invdc,
    const float* __restrict__ topv, const int* __restrict__ topi,
    float* __restrict__ A0) {
  int row = blockIdx.x;            // b*N + i
  int b = row / Nn;
  float idr = invdr[row];
  const float4* dc4 = reinterpret_cast<const float4*>(invdc + b * Nn);
  float4* out4 = reinterpret_cast<float4*>(A0 + (size_t)row * Nn);
  for (int j = threadIdx.x; j < Nn / 4; j += 256) {
    float4 c = dc4[j];
    float4 o = {idr * c.x, idr * c.y, idr * c.z, idr * c.w};
    out4[j] = o;
  }
  __syncthreads();
  if (threadIdx.x < NTOP) {
    int gidx = row * NTOP + threadIdx.x;
    int col = topi[gidx];
    float e = __expf(10.f * topv[gidx]);
    A0[(size_t)row * Nn + col] = e * e * idr * invdc[b * Nn + col];
  }
}

extern "C" void kernel_launch(void* const* d_in, const int* in_sizes, int n_in,
                              void* d_out, int out_size, void* d_ws, size_t ws_size,
                              hipStream_t stream) {
  const float* fm     = (const float*)d_in[0];
  const float* Abank  = (const float*)d_in[1];
  const float* pw_w   = (const float*)d_in[2];
  const float* pw_b   = (const float*)d_in[3];
  const float* proj_w = (const float*)d_in[4];
  const float* proj_b = (const float*)d_in[5];
  const float* r      = (const float*)d_in[6];
  const float* Mmat   = (const float*)d_in[7];
  const float* P      = (const float*)d_in[8];
  float* out = (float*)d_out;
  float* E  = out;
  float* A0 = out + (size_t)Bb * Nn * Dd;
  // fp16 S aliases into the A0 output region (read fully by k_topk before
  // k_basefix overwrites A0) — zero extra workspace.
  __half* S16 = (__half*)A0;

  float* ws = (float*)d_ws;
  float* y     = ws;                       //  1,605,632 floats (B*64*N*2, pair-interleaved)
  float* zt    = ws + 1605632;             //  6,422,528 (T*B*D*K, d-major)
  float* z     = ws + 8028160;             //  6,422,528 (T*B*K*D, normalized)
  float* wct   = ws + 14450688;            //     32,768
  float* bcv   = ws + 14483456;            //        128
  float* s_arr = ws + 14483584;            //     50,176
  float* g     = ws + 14533760;            //    401,408
  float* topv  = ws + 14935168;            //    401,408
  int*   topi  = (int*)(ws + 15336576);    //    401,408
  float* dr    = ws + 15737984;            //     12,544
  float* dc    = ws + 15750528;            //     12,544
  _Float16* E16 = (_Float16*)(ws + 15763072);   // 802,816 floats worth
  unsigned* offo = (unsigned*)(ws + 16565888);  // 50,176 u32 (T*N taps)
  float2*   wo   = (float2*)(ws + 16616064);    // 50,176 float2

  hipLaunchKernelGGL(k_prep, dim3(321), dim3(256), 0, stream,
                     pw_w, pw_b, proj_w, proj_b, Abank, wct, bcv, offo, wo, dc);
  hipLaunchKernelGGL(k_mix, dim3(392), dim3(256), 0, stream, fm, wct, y);
  hipLaunchKernelGGL(k_fused_pool, dim3(1024), dim3(256), 0, stream, y, offo, wo, bcv, zt);
  hipLaunchKernelGGL(k_znorm, dim3(64 * 14), dim3(256), 0, stream, zt, r, z, s_arr);
  hipLaunchKernelGGL(k_gemb, dim3(Bb * Kk), dim3(128), 0, stream, z, s_arr, g);
  hipLaunchKernelGGL(k_E, dim3(Bb * Nn / 2), dim3(128), 0, stream, Mmat, g, E, E16);
  hipLaunchKernelGGL(k_saff, dim3(Bb * 1225), dim3(256), 0, stream, E16, S16);
  hipLaunchKernelGGL(k_topk, dim3(Bb * Nn), dim3(256), 0, stream, S16, E, P, topv, topi, dr, dc);
  hipLaunchKernelGGL(k_inv, dim3(49), dim3(256), 0, stream, dr, dc);
  hipLaunchKernelGGL(k_basefix, dim3(Bb * Nn), dim3(256), 0, stream, dr, dc, topv, topi, A0);
}

// Round 9
// 415.695 us; speedup vs baseline: 1.0440x; 1.0440x over previous
//
#include <hip/hip_runtime.h>
#include <hip/hip_bf16.h>
#include <hip/hip_fp16.h>

#define Hh 56
#define Ww 56
#define Cc 256
#define Tt 16
#define Bb 4
#define Nn 3136
#define Kk 784
#define KX 28
#define Dd 128
#define Mc 64
#define NTOP 32

typedef __attribute__((ext_vector_type(8))) _Float16 f16x8;
typedef __attribute__((ext_vector_type(4))) float f32x4;

// ---- K_prep: fused {wc (blocks 0..255), coords (256..271), dcinit (272..320)}
__global__ __launch_bounds__(256) void k_prep(
    const float* __restrict__ pw_w, const float* __restrict__ pw_b,
    const float* __restrict__ proj_w, const float* __restrict__ proj_b,
    const float* __restrict__ Abank,
    float* __restrict__ wct, float* __restrict__ bc,
    unsigned* __restrict__ offo, float2* __restrict__ wo,
    float* __restrict__ dc) {
  int blk = blockIdx.x;
  if (blk < 256) {
    int c = blk;
    int d = threadIdx.x;
    if (d < 128) {
      float acc = 0.f;
      for (int m = 0; m < Mc; ++m) acc += proj_w[d * Mc + m] * pw_w[m * Cc + c];
      wct[c * Dd + d] = acc;
      if (c == 0) {
        float bb = proj_b[d];
        for (int m = 0; m < Mc; ++m) bb += proj_w[d * Mc + m] * pw_b[m];
        bc[d] = bb;
      }
    }
  } else if (blk < 272) {
    int t = blk - 256;
    const float* A = Abank + t * 6;
    float a00 = A[0], a01 = A[1], a02 = A[2], a10 = A[3], a11 = A[4], a12 = A[5];
    for (int e = threadIdx.x; e < Nn; e += 256) {
      int h = e / 56, w = e - h * 56;
      float gx = (2.0f * w + 1.0f) / 56.0f - 1.0f;
      float gy = (2.0f * h + 1.0f) / 56.0f - 1.0f;
      float u = a00 * gx + a01 * gy + a02;
      float v = a10 * gx + a11 * gy + a12;
      float ix = ((u + 1.0f) * 56.0f - 1.0f) * 0.5f;
      float iy = ((v + 1.0f) * 56.0f - 1.0f) * 0.5f;
      float x0f = floorf(ix), y0f = floorf(iy);
      int x0 = (int)x0f, y0 = (int)y0f;
      int x0c = min(max(x0, 0), 55), x1c = min(max(x0 + 1, 0), 55);
      int y0c = min(max(y0, 0), 55), y1c = min(max(y0 + 1, 0), 55);
      offo[t * Nn + e] = (y0c * 56 + x0c) | ((x1c - x0c) << 12) | ((y1c - y0c) << 13);
      float2 wv2;
      wv2.x = ix - x0f;
      wv2.y = iy - y0f;
      wo[t * Nn + e] = wv2;
    }
  } else {
    int i = (blk - 272) * 256 + threadIdx.x;
    if (i < Bb * Nn) dc[i] = (float)Nn;
  }
}

// ---- K_mix: channel mix FIRST, pair-interleaved output. b128 LDS reads ------
__global__ __launch_bounds__(256) void k_mix(
    const float* __restrict__ fm, const float* __restrict__ wct, float* __restrict__ y) {
  int blk = blockIdx.x;
  int b = blk / 98;
  int n0 = (blk % 98) * 32;
  int tid = threadIdx.x;
  int d = tid & 127;
  int ng = tid >> 7;               // 0..1 -> k-half of 16
  __shared__ __align__(16) float fm_s[64][32];
  __shared__ float wc_s[64 * Dd];
  float acc[16];
#pragma unroll
  for (int j = 0; j < 16; ++j) acc[j] = 0.f;
  const float* fb = fm + (size_t)b * Cc * Nn;
  for (int c0 = 0; c0 < Cc; c0 += 64) {
    for (int i = tid; i < 64 * 32; i += 256) {
      int c = i >> 5, kx = i & 31;
      fm_s[c][kx] = fb[(size_t)(c0 + c) * Nn + n0 + kx];
    }
    for (int i = tid; i < 64 * Dd; i += 256) wc_s[i] = wct[c0 * Dd + i];
    __syncthreads();
    for (int c = 0; c < 64; ++c) {
      float w = wc_s[c * Dd + d];
      const float4* fr = reinterpret_cast<const float4*>(&fm_s[c][ng * 16]);
      float4 f0 = fr[0], f1 = fr[1], f2 = fr[2], f3 = fr[3];
      acc[0]  += f0.x * w; acc[1]  += f0.y * w; acc[2]  += f0.z * w; acc[3]  += f0.w * w;
      acc[4]  += f1.x * w; acc[5]  += f1.y * w; acc[6]  += f1.z * w; acc[7]  += f1.w * w;
      acc[8]  += f2.x * w; acc[9]  += f2.y * w; acc[10] += f2.z * w; acc[11] += f2.w * w;
      acc[12] += f3.x * w; acc[13] += f3.y * w; acc[14] += f3.z * w; acc[15] += f3.w * w;
    }
    __syncthreads();
  }
  size_t base = (((size_t)b * 64 + (d >> 1)) * Nn + n0 + ng * 16) * 2 + (d & 1);
#pragma unroll
  for (int j = 0; j < 16; ++j) y[base + 2 * j] = acc[j];
}

// ---- K1: fused warp+bilinear+9x9/s2 pool, ky-TILED for occupancy ------------
// grid: b(4) x pg(32 of 2 pairs) x t(16) x kyq(4 of 7 ky) = 8192 blocks
// Tile needs warped rows 2*ky0-4 .. 2*ky0+16 (<=21 of 56) -> LDS 14.1KB ->
// 8 blocks/CU, full 32-wave occupancy. Pool arithmetic order identical.
__global__ __launch_bounds__(256, 8) void k_fused_pool(
    const float* __restrict__ yraw, const unsigned* __restrict__ offo,
    const float2* __restrict__ wo, const float* __restrict__ bc,
    float* __restrict__ zt) {
  const float2* y2 = reinterpret_cast<const float2*>(yraw);
  int idx = blockIdx.x;
  int b = idx & 3;
  int pg = (idx >> 2) & 31;        // 32 groups x 2 pairs = all 64 pairs
  int t = (idx >> 7) & 15;
  int kq = idx >> 11;              // 0..3
  int ky0 = kq * 7;
  int hlo = max(0, 2 * ky0 - 4);
  int hhi = min(55, 2 * ky0 + 16);
  int nh = hhi - hlo + 1;          // <= 21
  __shared__ float2 wsm[21 * 56];
  __shared__ float2 rowp[21 * 28];
  int tid = threadIdx.x;
  const unsigned* offp = offo + t * Nn + hlo * 56;
  const float2* wp = wo + t * Nn + hlo * 56;
  int npix = nh * 56;
  int nrp = nh * 28;
  for (int pp = 0; pp < 2; ++pp) {
    int dp = pg * 2 + pp;                       // channel pair 0..63
    const float2* fc = y2 + ((size_t)b * 64 + dp) * Nn;
    float b0 = bc[dp * 2], b1 = bc[dp * 2 + 1];
    // stage A: warped rows hlo..hhi -> wsm (local row index)
    for (int e = tid; e < npix; e += 256) {
      unsigned pk = offp[e];
      int base = pk & 4095;
      int dx = (pk >> 12) & 1;
      int dyy = (pk & (1u << 13)) ? 56 : 0;
      float2 v00 = fc[base], v01 = fc[base + dx];
      float2 v10 = fc[base + dyy], v11 = fc[base + dyy + dx];
      float2 wv = wp[e];
      float wx = wv.x, wy = wv.y;
      float tx = v00.x + wx * (v01.x - v00.x);
      float bx = v10.x + wx * (v11.x - v10.x);
      float ty = v00.y + wx * (v01.y - v00.y);
      float by = v10.y + wx * (v11.y - v10.y);
      float2 o;
      o.x = tx + wy * (bx - tx);
      o.y = ty + wy * (by - ty);
      wsm[e] = o;
    }
    __syncthreads();
    // stage B: row pool (horizontal 9, stride 2) for local rows
    for (int e = tid; e < nrp; e += 256) {
      int lh = e / 28, kx = e - lh * 28;
      int xs = 2 * kx - 4;
      int lo = max(xs, 0), hi = min(xs + 8, 55);
      float sx = 0.f, sy = 0.f;
      const float2* wr = wsm + lh * 56;
      for (int x = lo; x <= hi; ++x) { float2 v = wr[x]; sx += v.x; sy += v.y; }
      float2 o; o.x = sx; o.y = sy;
      rowp[e] = o;
    }
    __syncthreads();
    // stage C: col pool (vertical 9, stride 2) for ky0..ky0+6
    float* zo0 = zt + ((size_t)(t * Bb + b) * Dd + dp * 2) * Kk + ky0 * 28;
    float* zo1 = zo0 + Kk;
    for (int e = tid; e < 7 * 28; e += 256) {
      int kyl = e / 28, kx = e - kyl * 28;
      int ky = ky0 + kyl;
      int ys = 2 * ky - 4;
      int lo = max(ys, 0), hi = min(ys + 8, 55);
      float sx = 0.f, sy = 0.f;
      for (int h = lo; h <= hi; ++h) {
        float2 rv = rowp[(h - hlo) * 28 + kx];
        sx += rv.x; sy += rv.y;
      }
      zo0[e] = sx * (1.0f / 81.0f) + b0;
      zo1[e] = sy * (1.0f / 81.0f) + b1;
    }
    __syncthreads();
  }
}

// ---- K4: transpose zt -> z (normalized, [tb][k][d]) + s = zn . r ------------
__global__ __launch_bounds__(256) void k_znorm(
    const float* __restrict__ zt, const float* __restrict__ r,
    float* __restrict__ z, float* __restrict__ s_arr) {
  int tb = blockIdx.x / 14;
  int k0 = (blockIdx.x % 14) * 56;
  int tid = threadIdx.x;
  __shared__ float ls[56 * 129];
  const float* zb = zt + (size_t)tb * Dd * Kk + k0;
  for (int i = tid; i < Dd * 56; i += 256) {
    int d = i / 56, kk = i - d * 56;
    ls[kk * 129 + d] = zb[(size_t)d * Kk + kk];
  }
  int lane = tid & 63;
  int wvv = tid >> 6;              // 0..3
  float r0 = r[lane], r1 = r[lane + 64];
  __syncthreads();
  for (int p = 0; p < 14; ++p) {
    int k = p * 4 + wvv;
    float z0 = ls[k * 129 + lane];
    float z1 = ls[k * 129 + 64 + lane];
    float ss = z0 * z0 + z1 * z1;
    for (int off = 32; off; off >>= 1) ss += __shfl_xor(ss, off);
    float inv = 1.0f / fmaxf(sqrtf(ss), 1e-6f);
    z0 *= inv; z1 *= inv;
    float* zr = z + ((size_t)tb * Kk + k0 + k) * Dd;
    zr[lane] = z0;
    zr[lane + 64] = z1;
    float sd = z0 * r0 + z1 * r1;
    for (int off = 32; off; off >>= 1) sd += __shfl_xor(sd, off);
    if (lane == 0) s_arr[(size_t)tb * Kk + k0 + k] = sd;
  }
}

// ---------------- K5: softmax over T, g_emb ----------------------------------
__global__ __launch_bounds__(128) void k_gemb(
    const float* __restrict__ z, const float* __restrict__ s_arr, float* __restrict__ g) {
  int blk = blockIdx.x;            // b*784 + k
  int b = blk / Kk, k = blk % Kk;
  int d = threadIdx.x;
  float sv[Tt];
  float mx = -3.4e38f;
#pragma unroll
  for (int t = 0; t < Tt; ++t) {
    sv[t] = s_arr[(t * Bb + b) * Kk + k];
    mx = fmaxf(mx, sv[t]);
  }
  float sum = 0.f;
#pragma unroll
  for (int t = 0; t < Tt; ++t) {
    sv[t] = expf(10.0f * (sv[t] - mx));
    sum += sv[t];
  }
  float isum = 1.0f / sum;
  float acc = 0.f;
#pragma unroll
  for (int t = 0; t < Tt; ++t)
    acc += sv[t] * isum * z[((size_t)(t * Bb + b) * Kk + k) * Dd + d];
  g[((size_t)b * Kk + k) * Dd + d] = acc;
}

// ---- K6: E = normalize(M @ g), also emits fp16 copy. 2 rows per block -------
__global__ __launch_bounds__(128) void k_E(
    const float* __restrict__ Mmat, const float* __restrict__ g,
    float* __restrict__ E, _Float16* __restrict__ E16) {
  int row = blockIdx.x * 2 + (threadIdx.x >> 6);   // b*N + n
  int b = row / Nn, n = row % Nn;
  int y = n / Ww, x = n % Ww;
  int x0 = x >> 1, y0 = y >> 1;
  int x1 = min(x0 + 1, 27), y1 = min(y0 + 1, 27);
  bool hx = (x1 != x0), hy = (y1 != y0);
  int k00 = y0 * 28 + x0, k01 = y0 * 28 + x1, k10 = y1 * 28 + x0, k11 = y1 * 28 + x1;
  const float* Mr = Mmat + (size_t)n * Kk;
  float m00 = Mr[k00];
  float m01 = hx ? Mr[k01] : 0.f;
  float m10 = hy ? Mr[k10] : 0.f;
  float m11 = (hx && hy) ? Mr[k11] : 0.f;
  const float* gb = g + (size_t)b * Kk * Dd;
  int lane = threadIdx.x & 63;
  int l2 = lane + 64;
  float a0 = m00 * gb[k00 * Dd + lane] + m01 * gb[k01 * Dd + lane] +
             m10 * gb[k10 * Dd + lane] + m11 * gb[k11 * Dd + lane];
  float a1 = m00 * gb[k00 * Dd + l2] + m01 * gb[k01 * Dd + l2] +
             m10 * gb[k10 * Dd + l2] + m11 * gb[k11 * Dd + l2];
  float ss = a0 * a0 + a1 * a1;
  for (int off = 32; off; off >>= 1) ss += __shfl_xor(ss, off);
  float inv = 1.0f / fmaxf(sqrtf(ss), 1e-6f);
  float e0 = a0 * inv, e1 = a1 * inv;
  E[(size_t)row * Dd + lane] = e0;
  E[(size_t)row * Dd + l2] = e1;
  E16[(size_t)row * Dd + lane] = (_Float16)e0;
  E16[(size_t)row * Dd + l2] = (_Float16)e1;
}

// ---- K7: Saff = (E E^T) * G -> fp16 via MFMA f16 (fp32 accum) ---------------
// Direct main store; mirror via LDS transpose.
__global__ __launch_bounds__(256) void k_saff(
    const _Float16* __restrict__ E16, __half* __restrict__ S) {
  int blk = blockIdx.x;
  int b = blk / 1225;
  int rem = blk % 1225;
  int ti0 = (int)((sqrtf(8.f * rem + 1.f) - 1.f) * 0.5f);
  while ((ti0 + 1) * (ti0 + 2) / 2 <= rem) ++ti0;
  while (ti0 * (ti0 + 1) / 2 > rem) --ti0;
  int tj0 = rem - ti0 * (ti0 + 1) / 2;   // tj0 <= ti0
  int i0 = ti0 * 64, j0 = tj0 * 64;
  int wave = threadIdx.x >> 6, lane = threadIdx.x & 63;
  int wr = wave >> 1, wc = wave & 1;
  int lr = lane & 15, lk = lane >> 4;    // frag row/col, k-group
  int ibase = i0 + wr * 32;
  int jbase = j0 + wc * 32;
  const _Float16* Eb = E16 + (size_t)b * Nn * Dd;
  __shared__ __half tile[64][66];        // transposed tile for mirror store
  f32x4 acc00 = {0.f, 0.f, 0.f, 0.f};
  f32x4 acc01 = acc00, acc10 = acc00, acc11 = acc00;
#pragma unroll
  for (int ks = 0; ks < 4; ++ks) {
    int ko = ks * 32 + lk * 8;
    f16x8 a0 = *reinterpret_cast<const f16x8*>(Eb + (size_t)(ibase + lr) * Dd + ko);
    f16x8 a1 = *reinterpret_cast<const f16x8*>(Eb + (size_t)(ibase + 16 + lr) * Dd + ko);
    f16x8 b0 = *reinterpret_cast<const f16x8*>(Eb + (size_t)(jbase + lr) * Dd + ko);
    f16x8 b1 = *reinterpret_cast<const f16x8*>(Eb + (size_t)(jbase + 16 + lr) * Dd + ko);
    acc00 = __builtin_amdgcn_mfma_f32_16x16x32_f16(a0, b0, acc00, 0, 0, 0);
    acc01 = __builtin_amdgcn_mfma_f32_16x16x32_f16(a0, b1, acc01, 0, 0, 0);
    acc10 = __builtin_amdgcn_mfma_f32_16x16x32_f16(a1, b0, acc10, 0, 0, 0);
    acc11 = __builtin_amdgcn_mfma_f32_16x16x32_f16(a1, b1, acc11, 0, 0, 0);
  }
  size_t ob = (size_t)b * Nn * Nn;
  int gj[2];
  float xj[2], yj[2];
#pragma unroll
  for (int tj = 0; tj < 2; ++tj) {
    gj[tj] = jbase + tj * 16 + lr;
    int yv = gj[tj] / 56;
    yj[tj] = (float)yv;
    xj[tj] = (float)(gj[tj] - yv * 56);
  }
  bool mirror = (i0 != j0);
#pragma unroll
  for (int ti = 0; ti < 2; ++ti) {
#pragma unroll
    for (int q = 0; q < 4; ++q) {
      int iloc = wr * 32 + ti * 16 + lk * 4 + q;
      int gi = i0 + iloc;
      int yiv = gi / 56;
      float yi = (float)yiv;
      float xi = (float)(gi - yiv * 56);
#pragma unroll
      for (int tj = 0; tj < 2; ++tj) {
        float a;
        if (ti == 0 && tj == 0) a = acc00[q];
        else if (ti == 0 && tj == 1) a = acc01[q];
        else if (ti == 1 && tj == 0) a = acc10[q];
        else a = acc11[q];
        float dx = xi - xj[tj];
        float dy = yi - yj[tj];
        float gg = 1.0f - __expf(-(dx * dx + dy * dy) * (1.0f / 18.0f));
        __half hv = __float2half(a * gg);
        S[ob + (size_t)gi * Nn + gj[tj]] = hv;
        int jloc = wc * 32 + tj * 16 + lr;
        tile[jloc][iloc] = hv;               // transposed stash for mirror
      }
    }
  }
  if (mirror) {
    __syncthreads();
    for (int e = threadIdx.x; e < 64 * 32; e += 256) {
      int row = e >> 5, c2 = e & 31;
      unsigned v = *reinterpret_cast<const unsigned*>(&tile[row][c2 * 2]);
      *reinterpret_cast<unsigned*>(&S[ob + (size_t)(j0 + row) * Nn + i0 + c2 * 2]) = v;
    }
  }
}

// ---- K8: exact top-32 per row: 2-pass radix select on fp16 keys (wave-scan),
//      then exact fp32 recompute of the 32 selected values from E ------------
__global__ __launch_bounds__(256) void k_topk(
    const __half* __restrict__ S16, const float* __restrict__ E,
    const float* __restrict__ P, float* __restrict__ topv, int* __restrict__ topi,
    float* __restrict__ dr, float* __restrict__ dc) {
  int row = blockIdx.x;
  int b = row / Nn, irow = row % Nn;
  int tid = threadIdx.x;
  const unsigned* Sr = reinterpret_cast<const unsigned*>(S16 + (size_t)row * Nn);
  __shared__ unsigned hist[256 * 8];
  __shared__ unsigned wtot[4];
  __shared__ unsigned bcast[2];
  __shared__ unsigned sel_eq, sel_slot;
  __shared__ int sel_idx[NTOP];
  __shared__ float drow_s;
  unsigned pk[7];                  // 2 fp16 monotone keys per u32
#pragma unroll
  for (int j = 0; j < 7; ++j) {
    int c2 = tid + 256 * j;
    unsigned u = (c2 < Nn / 2) ? Sr[c2] : 0u;
    unsigned h0 = u & 0xFFFFu, h1 = u >> 16;
    unsigned k0 = h0 ^ ((h0 & 0x8000u) ? 0xFFFFu : 0x8000u);
    unsigned k1 = h1 ^ ((h1 & 0x8000u) ? 0xFFFFu : 0x8000u);
    if (c2 >= Nn / 2) { k0 = 0u; k1 = 0u; }
    pk[j] = k0 | (k1 << 16);
  }
  if (tid == 0) { sel_eq = 0; sel_slot = 0; drow_s = 0.f; }
  int lane = tid & 63, wvq = tid >> 6;
  unsigned prefix = 0;
  unsigned k = NTOP;
  for (int pass = 0; pass < 2; ++pass) {
    int shift = 8 - 8 * pass;
    unsigned pmask = pass ? 0xFF00u : 0u;
#pragma unroll
    for (int i = 0; i < 8; ++i) hist[tid * 8 + i] = 0;
    __syncthreads();
#pragma unroll
    for (int j = 0; j < 7; ++j) {
      unsigned k0 = pk[j] & 0xFFFFu, k1 = pk[j] >> 16;
      if ((k0 & pmask) == (prefix & pmask))
        atomicAdd(&hist[((k0 >> shift) & 255u) * 8 + (tid & 7)], 1u);
      if ((k1 & pmask) == (prefix & pmask))
        atomicAdd(&hist[((k1 >> shift) & 255u) * 8 + (tid & 7)], 1u);
    }
    __syncthreads();
    unsigned cnt = 0;
#pragma unroll
    for (int i = 0; i < 8; ++i) cnt += hist[tid * 8 + i];
    unsigned run = cnt;
#pragma unroll
    for (int off2 = 1; off2 < 64; off2 <<= 1) {
      unsigned v = __shfl_down(run, off2);
      if (lane + off2 < 64) run += v;
    }
    if (lane == 0) wtot[wvq] = run;  // wave total
    __syncthreads();
    unsigned hi = 0;
    for (int w2 = wvq + 1; w2 < 4; ++w2) hi += wtot[w2];
    unsigned incl = run + hi;
    unsigned excl = incl - cnt;
    if (excl < k && k <= incl) {
      bcast[0] = prefix | ((unsigned)tid << shift);
      bcast[1] = k - excl;
    }
    __syncthreads();
    prefix = bcast[0];
    k = bcast[1];
    __syncthreads();
  }
  unsigned T = prefix;
#pragma unroll
  for (int j = 0; j < 7; ++j) {
    int c2 = tid + 256 * j;
    if (c2 < Nn / 2) {
      unsigned k0 = pk[j] & 0xFFFFu, k1 = pk[j] >> 16;
      bool take0 = (k0 > T) || (k0 == T && atomicAdd(&sel_eq, 1u) < k);
      if (take0) { unsigned slot = atomicAdd(&sel_slot, 1u); sel_idx[slot] = 2 * c2; }
      bool take1 = (k1 > T) || (k1 == T && atomicAdd(&sel_eq, 1u) < k);
      if (take1) { unsigned slot = atomicAdd(&sel_slot, 1u); sel_idx[slot] = 2 * c2 + 1; }
    }
  }
  __syncthreads();
  // exact recompute: 8 threads per selected entry
  int sel = tid >> 3, part = tid & 7;
  int col = sel_idx[sel];
  const float* Ei = E + ((size_t)b * Nn + irow) * Dd;
  const float* Ej = E + ((size_t)b * Nn + col) * Dd;
  float v = 0.f;
#pragma unroll
  for (int d0 = 0; d0 < 16; ++d0) {
    int d = part * 16 + d0;
    v += Ei[d] * Ej[d];
  }
  v += __shfl_xor(v, 1);
  v += __shfl_xor(v, 2);
  v += __shfl_xor(v, 4);
  if (part == 0) {
    float dx = P[irow * 2] - P[col * 2];
    float dy = P[irow * 2 + 1] - P[col * 2 + 1];
    float gg = 1.0f - __expf(-(dx * dx + dy * dy) * (1.0f / 18.0f));
    v *= gg;
    topv[(size_t)row * NTOP + sel] = v;
    topi[(size_t)row * NTOP + sel] = col;
    float e = __expf(10.f * v);
    atomicAdd(&dc[b * Nn + col], e - 1.f);
    atomicAdd(&drow_s, e);
  }
  __syncthreads();
  if (tid == 0) dr[row] = (float)(Nn - NTOP) + drow_s;
}

// ---- K10: A0 row = (1/dr_i) * (1/dc_j), then fix 32 entries (inv folded in) -
__global__ __launch_bounds__(256) void k_basefix(
    const float* __restrict__ dr, const float* __restrict__ dc,
    const float* __restrict__ topv, const int* __restrict__ topi,
    float* __restrict__ A0) {
  int row = blockIdx.x;            // b*N + i
  int b = row / Nn;
  float idr = 1.0f / dr[row];
  const float4* dc4 = reinterpret_cast<const float4*>(dc + b * Nn);
  float4* out4 = reinterpret_cast<float4*>(A0 + (size_t)row * Nn);
  for (int j = threadIdx.x; j < Nn / 4; j += 256) {
    float4 c = dc4[j];
    float4 o = {idr / c.x, idr / c.y, idr / c.z, idr / c.w};
    out4[j] = o;
  }
  __syncthreads();
  if (threadIdx.x < NTOP) {
    int gidx = row * NTOP + threadIdx.x;
    int col = topi[gidx];
    float e = __expf(10.f * topv[gidx]);
    A0[(size_t)row * Nn + col] = e * e * idr / dc[b * Nn + col];
  }
}

extern "C" void kernel_launch(void* const* d_in, const int* in_sizes, int n_in,
                              void* d_out, int out_size, void* d_ws, size_t ws_size,
                              hipStream_t stream) {
  const float* fm     = (const float*)d_in[0];
  const float* Abank  = (const float*)d_in[1];
  const float* pw_w   = (const float*)d_in[2];
  const float* pw_b   = (const float*)d_in[3];
  const float* proj_w = (const float*)d_in[4];
  const float* proj_b = (const float*)d_in[5];
  const float* r      = (const float*)d_in[6];
  const float* Mmat   = (const float*)d_in[7];
  const float* P      = (const float*)d_in[8];
  float* out = (float*)d_out;
  float* E  = out;
  float* A0 = out + (size_t)Bb * Nn * Dd;
  // fp16 S aliases into the A0 output region (read fully by k_topk before
  // k_basefix overwrites A0) — zero extra workspace.
  __half* S16 = (__half*)A0;

  float* ws = (float*)d_ws;
  float* y     = ws;                       //  1,605,632 floats (B*64*N*2, pair-interleaved)
  float* zt    = ws + 1605632;             //  6,422,528 (T*B*D*K, d-major)
  float* z     = ws + 8028160;             //  6,422,528 (T*B*K*D, normalized)
  float* wct   = ws + 14450688;            //     32,768
  float* bcv   = ws + 14483456;            //        128
  float* s_arr = ws + 14483584;            //     50,176
  float* g     = ws + 14533760;            //    401,408
  float* topv  = ws + 14935168;            //    401,408
  int*   topi  = (int*)(ws + 15336576);    //    401,408
  float* dr    = ws + 15737984;            //     12,544
  float* dc    = ws + 15750528;            //     12,544
  _Float16* E16 = (_Float16*)(ws + 15763072);   // 802,816 floats worth
  unsigned* offo = (unsigned*)(ws + 16565888);  // 50,176 u32 (T*N taps)
  float2*   wo   = (float2*)(ws + 16616064);    // 50,176 float2

  hipLaunchKernelGGL(k_prep, dim3(321), dim3(256), 0, stream,
                     pw_w, pw_b, proj_w, proj_b, Abank, wct, bcv, offo, wo, dc);
  hipLaunchKernelGGL(k_mix, dim3(392), dim3(256), 0, stream, fm, wct, y);
  hipLaunchKernelGGL(k_fused_pool, dim3(8192), dim3(256), 0, stream, y, offo, wo, bcv, zt);
  hipLaunchKernelGGL(k_znorm, dim3(64 * 14), dim3(256), 0, stream, zt, r, z, s_arr);
  hipLaunchKernelGGL(k_gemb, dim3(Bb * Kk), dim3(128), 0, stream, z, s_arr, g);
  hipLaunchKernelGGL(k_E, dim3(Bb * Nn / 2), dim3(128), 0, stream, Mmat, g, E, E16);
  hipLaunchKernelGGL(k_saff, dim3(Bb * 1225), dim3(256), 0, stream, E16, S16);
  hipLaunchKernelGGL(k_topk, dim3(Bb * Nn), dim3(256), 0, stream, S16, E, P, topv, topi, dr, dc);
  hipLaunchKernelGGL(k_basefix, dim3(Bb * Nn), dim3(256), 0, stream, dr, dc, topv, topi, A0);
}